// Round 1
// baseline (2405.784 us; speedup 1.0000x reference)
//
#include <hip/hip_runtime.h>

#define NLENC 500000
#define DIM   128
#define BSZ   256     // BATCH_SIZE * CLIPS_NUM
#define BATCH 64
#define CLIPS 4
#define NNEG  252     // (BATCH-1)*CLIPS
#define NLOG  253
#define KNN   8
#define NBLK  512
#define CHUNK ((NLENC + NBLK - 1) / NBLK)   // 977

// ---------------------------------------------------------------------------
// Kernel A: fused sim = x @ memory.T with per-row top-8 over this block's chunk
// lane-per-x-row: x row lives in 128 VGPRs; memory row is read at wave-uniform
// addresses (scalar loads). Per-lane register top-8, written per (row, block).
// ---------------------------------------------------------------------------
__global__ __launch_bounds__(256) void topk_partial(
    const float* __restrict__ x, const float* __restrict__ mem,
    float* __restrict__ cand_val, int* __restrict__ cand_idx)
{
    const int row = threadIdx.x;            // 0..255, one x-row per lane
    float xr[DIM];
    #pragma unroll
    for (int k = 0; k < DIM; k += 4) {
        const float4 v = *reinterpret_cast<const float4*>(x + row * DIM + k);
        xr[k] = v.x; xr[k+1] = v.y; xr[k+2] = v.z; xr[k+3] = v.w;
    }

    float tv[KNN]; int tix[KNN];
    #pragma unroll
    for (int k = 0; k < KNN; ++k) { tv[k] = -1e30f; tix[k] = 0; }
    float vmin = -1e30f;

    const int m0 = blockIdx.x * CHUNK;
    const int m1 = min(m0 + CHUNK, NLENC);

#define TOPK_UPDATE(S, M)                                                  \
    if ((S) > vmin) {                                                      \
        int slot = 0; float mv = tv[0];                                    \
        _Pragma("unroll")                                                  \
        for (int k = 1; k < KNN; ++k) if (tv[k] < mv) { mv = tv[k]; slot = k; } \
        tv[slot] = (S); tix[slot] = (M);                                   \
        vmin = tv[0];                                                      \
        _Pragma("unroll")                                                  \
        for (int k = 1; k < KNN; ++k) vmin = fminf(vmin, tv[k]);           \
    }

    int m = m0;
    for (; m + 1 < m1; m += 2) {
        const float* r0 = mem + (size_t)m * DIM;
        const float* r1 = r0 + DIM;
        float a0 = 0.f, a1 = 0.f, a2 = 0.f, a3 = 0.f;
        float b0 = 0.f, b1 = 0.f, b2 = 0.f, b3 = 0.f;
        #pragma unroll
        for (int k = 0; k < DIM; k += 4) {
            a0 = fmaf(xr[k],   r0[k],   a0);
            a1 = fmaf(xr[k+1], r0[k+1], a1);
            a2 = fmaf(xr[k+2], r0[k+2], a2);
            a3 = fmaf(xr[k+3], r0[k+3], a3);
            b0 = fmaf(xr[k],   r1[k],   b0);
            b1 = fmaf(xr[k+1], r1[k+1], b1);
            b2 = fmaf(xr[k+2], r1[k+2], b2);
            b3 = fmaf(xr[k+3], r1[k+3], b3);
        }
        const float s0 = (a0 + a1) + (a2 + a3);
        const float s1 = (b0 + b1) + (b2 + b3);
        TOPK_UPDATE(s0, m)
        TOPK_UPDATE(s1, m + 1)
    }
    if (m < m1) {
        const float* r0 = mem + (size_t)m * DIM;
        float a0 = 0.f, a1 = 0.f, a2 = 0.f, a3 = 0.f;
        #pragma unroll
        for (int k = 0; k < DIM; k += 4) {
            a0 = fmaf(xr[k],   r0[k],   a0);
            a1 = fmaf(xr[k+1], r0[k+1], a1);
            a2 = fmaf(xr[k+2], r0[k+2], a2);
            a3 = fmaf(xr[k+3], r0[k+3], a3);
        }
        const float s0 = (a0 + a1) + (a2 + a3);
        TOPK_UPDATE(s0, m)
    }
#undef TOPK_UPDATE

    const size_t base = ((size_t)row * NBLK + blockIdx.x) * KNN;
    #pragma unroll
    for (int k = 0; k < KNN; ++k) { cand_val[base + k] = tv[k]; cand_idx[base + k] = tix[k]; }
}

// ---------------------------------------------------------------------------
// Kernel B: per-row merge of NBLK*8 candidates -> exact top-8 (tie: lower idx),
// then pos_logit = mean(top8 vals), dm_bs[row][d] = mean_k memory[yi_k][d]
// ---------------------------------------------------------------------------
__global__ __launch_bounds__(256) void topk_merge(
    const float* __restrict__ mem,
    const float* __restrict__ cand_val, const int* __restrict__ cand_idx,
    float* __restrict__ pos_logit, float* __restrict__ dm_bs)
{
    const int row = blockIdx.x;
    const int tid = threadIdx.x;
    const int NC = NBLK * KNN;   // 4096
    __shared__ float sv[NBLK * KNN];
    __shared__ int   si[NBLK * KNN];
    __shared__ float rv[256];
    __shared__ int   ri[256];
    __shared__ float bestv[KNN];
    __shared__ int   besti[KNN];

    for (int i = tid; i < NC; i += 256) {
        sv[i] = cand_val[(size_t)row * NC + i];
        si[i] = cand_idx[(size_t)row * NC + i];
    }
    __syncthreads();

    for (int it = 0; it < KNN; ++it) {
        float lv = -1e30f; int li = 0x7fffffff;
        for (int i = tid; i < NC; i += 256) {
            const float v = sv[i]; const int ix = si[i];
            if (v > lv || (v == lv && ix < li)) { lv = v; li = ix; }
        }
        rv[tid] = lv; ri[tid] = li;
        __syncthreads();
        for (int s = 128; s > 0; s >>= 1) {
            if (tid < s) {
                const float v = rv[tid + s]; const int ix = ri[tid + s];
                if (v > rv[tid] || (v == rv[tid] && ix < ri[tid])) { rv[tid] = v; ri[tid] = ix; }
            }
            __syncthreads();
        }
        if (tid == 0) { bestv[it] = rv[0]; besti[it] = ri[0]; }
        __syncthreads();
        const int sel = ri[0];
        for (int i = tid; i < NC; i += 256) {
            if (si[i] == sel) sv[i] = -1e30f;
        }
        __syncthreads();
    }

    if (tid == 0) {
        float s = 0.f;
        #pragma unroll
        for (int k = 0; k < KNN; ++k) s += bestv[k];
        pos_logit[row] = s / (float)KNN;
    }
    if (tid < DIM) {
        float s = 0.f;
        #pragma unroll
        for (int k = 0; k < KNN; ++k) s += mem[(size_t)besti[k] * DIM + tid];
        dm_bs[(size_t)row * DIM + tid] = s / (float)KNN;
    }
}

// ---------------------------------------------------------------------------
// Kernel C: neg logits + exp(logits/T) raw into d_out, per-row sum
// ---------------------------------------------------------------------------
__global__ __launch_bounds__(256) void neg_exp(
    const float* __restrict__ x, const int* __restrict__ neg_indices,
    const float* __restrict__ pos_logit,
    float* __restrict__ outs_raw, float* __restrict__ rowsum)
{
    const int b = blockIdx.x, tid = threadIdx.x;
    __shared__ float xb[DIM];
    if (tid < DIM) xb[tid] = x[b * DIM + tid];
    __syncthreads();

    float raw = 0.f;
    if (tid < NLOG) {
        float lg;
        if (tid == 0) {
            lg = pos_logit[b];
        } else {
            const int n = neg_indices[b * NNEG + (tid - 1)];
            const float* xn = x + (size_t)n * DIM;
            float a0 = 0.f, a1 = 0.f, a2 = 0.f, a3 = 0.f;
            #pragma unroll
            for (int k = 0; k < DIM; k += 4) {
                a0 = fmaf(xb[k],   xn[k],   a0);
                a1 = fmaf(xb[k+1], xn[k+1], a1);
                a2 = fmaf(xb[k+2], xn[k+2], a2);
                a3 = fmaf(xb[k+3], xn[k+3], a3);
            }
            lg = (a0 + a1) + (a2 + a3);
        }
        raw = expf(lg / 0.07f);
        outs_raw[(size_t)b * NLOG + tid] = raw;
    }

    __shared__ float red[256];
    red[tid] = raw;
    __syncthreads();
    for (int s = 128; s > 0; s >>= 1) {
        if (tid < s) red[tid] += red[tid + s];
        __syncthreads();
    }
    if (tid == 0) rowsum[b] = red[0];
}

// ---------------------------------------------------------------------------
// Kernel D: Z from rowsums, probs (Z cancels), scale outs in-place
// ---------------------------------------------------------------------------
__global__ __launch_bounds__(256) void finalize(
    float* __restrict__ outs, const float* __restrict__ rowsum)
{
    const int tid = threadIdx.x;  // 256 = BSZ
    __shared__ float red[256];
    __shared__ float Zs;
    const float rs = rowsum[tid];
    red[tid] = rs;
    __syncthreads();
    for (int s = 128; s > 0; s >>= 1) {
        if (tid < s) red[tid] += red[tid + s];
        __syncthreads();
    }
    if (tid == 0) Zs = red[0] / (float)(BSZ * NLOG) * (float)NLENC;
    __syncthreads();
    const float Z = Zs;

    const float ratio = outs[(size_t)tid * NLOG] / rs;
    __syncthreads();
    red[tid] = ratio;
    __syncthreads();
    for (int s = 128; s > 0; s >>= 1) {
        if (tid < s) red[tid] += red[tid + s];
        __syncthreads();
    }
    if (tid == 0) outs[BSZ * NLOG] = red[0] / (float)BSZ;

    for (int i = tid; i < BSZ * NLOG; i += 256) outs[i] /= Z;
}

// ---------------------------------------------------------------------------
// Kernel E1: EMA-updated rows -> small ws (before the big copy overwrites scratch)
// ---------------------------------------------------------------------------
__global__ __launch_bounds__(128) void update_rows(
    const float* __restrict__ mem, const int* __restrict__ idxs,
    const float* __restrict__ dm_bs, float* __restrict__ upd)
{
    const int j = blockIdx.x;    // 0..63
    const int d = threadIdx.x;   // 0..127
    float nd = 0.f;
    #pragma unroll
    for (int c = 0; c < CLIPS; ++c) nd += dm_bs[(size_t)(c * BATCH + j) * DIM + d];
    nd *= (1.0f / CLIPS);
    const float old = mem[(size_t)idxs[j] * DIM + d];
    const float v = old * 0.5f + 0.5f * nd;
    __shared__ float red[128];
    red[d] = v * v;
    __syncthreads();
    for (int s = 64; s > 0; s >>= 1) {
        if (d < s) red[d] += red[d + s];
        __syncthreads();
    }
    upd[(size_t)j * DIM + d] = v / sqrtf(red[0]);
}

// ---------------------------------------------------------------------------
// Kernel E2: bulk copy memory -> out (scalar dword: dst is 4-mod-16 misaligned)
// ---------------------------------------------------------------------------
__global__ __launch_bounds__(256) void copy_mem(
    const float* __restrict__ src, float* __restrict__ dst, int n)
{
    int i = blockIdx.x * blockDim.x + threadIdx.x;
    const int stride = gridDim.x * blockDim.x;
    for (; i < n; i += stride) dst[i] = src[i];
}

// ---------------------------------------------------------------------------
// Kernel E3: scatter updated rows (last-duplicate wins, matching .at[].set)
// ---------------------------------------------------------------------------
__global__ __launch_bounds__(128) void scatter_rows(
    const int* __restrict__ idxs, const float* __restrict__ upd,
    float* __restrict__ out_mem)
{
    const int j = blockIdx.x;
    const int d = threadIdx.x;
    const int my = idxs[j];
    for (int jj = j + 1; jj < BATCH; ++jj)
        if (idxs[jj] == my) return;   // a later duplicate overrides this row
    out_mem[(size_t)my * DIM + d] = upd[(size_t)j * DIM + d];
}

extern "C" void kernel_launch(void* const* d_in, const int* in_sizes, int n_in,
                              void* d_out, int out_size, void* d_ws, size_t ws_size,
                              hipStream_t stream)
{
    const float* x    = (const float*)d_in[0];
    const int*   idxs = (const int*)d_in[1];
    const int*   neg  = (const int*)d_in[2];
    const float* mem  = (const float*)d_in[3];

    float* out     = (float*)d_out;
    float* out_mem = out + (size_t)BSZ * NLOG + 1;      // 64,000,000 floats

    // big scratch lives inside out_mem (overwritten by copy_mem afterwards)
    float* scr      = out_mem + 32000000;
    float* cand_val = scr;                               // 1,048,576 f
    int*   cand_idx = (int*)(scr + 1048576);             // 1,048,576 i
    float* pos      = scr + 2097152;                     // 256
    float* dm_bs    = pos + 256;                         // 32768
    float* rowsum   = dm_bs + (size_t)BSZ * DIM;         // 256
    float* upd      = (float*)d_ws;                      // 8192 floats = 32 KB

    hipLaunchKernelGGL(topk_partial, dim3(NBLK), dim3(256), 0, stream, x, mem, cand_val, cand_idx);
    hipLaunchKernelGGL(topk_merge,   dim3(BSZ),  dim3(256), 0, stream, mem, cand_val, cand_idx, pos, dm_bs);
    hipLaunchKernelGGL(neg_exp,      dim3(BSZ),  dim3(256), 0, stream, x, neg, pos, out, rowsum);
    hipLaunchKernelGGL(finalize,     dim3(1),    dim3(256), 0, stream, out, rowsum);
    hipLaunchKernelGGL(update_rows,  dim3(BATCH), dim3(128), 0, stream, mem, idxs, dm_bs, upd);
    hipLaunchKernelGGL(copy_mem,     dim3(2048), dim3(256), 0, stream, mem, out_mem, NLENC * DIM);
    hipLaunchKernelGGL(scatter_rows, dim3(BATCH), dim3(128), 0, stream, idxs, upd, out_mem);
}

// Round 2
// 579.265 us; speedup vs baseline: 4.1532x; 4.1532x over previous
//
#include <hip/hip_runtime.h>

#define NLENC 500000
#define DIM   128
#define BSZ   256     // BATCH_SIZE * CLIPS_NUM
#define BATCH 64
#define CLIPS 4
#define NNEG  252     // (BATCH-1)*CLIPS
#define NLOG  253
#define KNN   8

#define SUBSTRIDE 64
#define SUBN      7813          // ceil(500000/64)
#define SUB_NBLK  512
#define SUB_ROWS  16            // rows per block (512*16 >= 7813)
#define CAP       4096
#define NCHUNK    (NLENC / 16)  // 31250
#define MARGIN    0.006f

typedef short bf16x8 __attribute__((ext_vector_type(8)));
typedef float f32x4  __attribute__((ext_vector_type(4)));

__device__ inline unsigned short f2bf(float f) {
    unsigned int u = __float_as_uint(f);
    u += 0x7fffu + ((u >> 16) & 1u);       // round-to-nearest-even
    return (unsigned short)(u >> 16);
}

// ---------------------------------------------------------------------------
// convert f32 -> bf16 (vectorized), used for memory bank and x
// ---------------------------------------------------------------------------
__global__ __launch_bounds__(256) void convert_bf16(
    const float* __restrict__ src, unsigned short* __restrict__ dst, int n)
{
    const int stride = gridDim.x * blockDim.x * 4;
    for (int i = (blockIdx.x * blockDim.x + threadIdx.x) * 4; i < n; i += stride) {
        const float4 v = *reinterpret_cast<const float4*>(src + i);
        ushort4 o;
        o.x = f2bf(v.x); o.y = f2bf(v.y); o.z = f2bf(v.z); o.w = f2bf(v.w);
        *reinterpret_cast<ushort4*>(dst + i) = o;
    }
}

// ---------------------------------------------------------------------------
// subsample top-8 (stride-64 rows) in exact f32 — gives per-row threshold
// ---------------------------------------------------------------------------
#define TOPK_UPDATE(S, M)                                                  \
    if ((S) > vmin) {                                                      \
        int slot = 0; float mv = tv[0];                                    \
        _Pragma("unroll")                                                  \
        for (int k = 1; k < KNN; ++k) if (tv[k] < mv) { mv = tv[k]; slot = k; } \
        tv[slot] = (S); tix[slot] = (M);                                   \
        vmin = tv[0];                                                      \
        _Pragma("unroll")                                                  \
        for (int k = 1; k < KNN; ++k) vmin = fminf(vmin, tv[k]);           \
    }

__global__ __launch_bounds__(256) void sub_topk(
    const float* __restrict__ x, const float* __restrict__ mem,
    float* __restrict__ scv, int* __restrict__ sci)
{
    const int row = threadIdx.x;
    float xr[DIM];
    #pragma unroll
    for (int k = 0; k < DIM; k += 4) {
        const float4 v = *reinterpret_cast<const float4*>(x + row * DIM + k);
        xr[k] = v.x; xr[k+1] = v.y; xr[k+2] = v.z; xr[k+3] = v.w;
    }
    float tv[KNN]; int tix[KNN];
    #pragma unroll
    for (int k = 0; k < KNN; ++k) { tv[k] = -1e30f; tix[k] = 0; }
    float vmin = -1e30f;

    const int i0 = blockIdx.x * SUB_ROWS;
    const int i1 = min(i0 + SUB_ROWS, SUBN);
    for (int i = i0; i < i1; ++i) {
        const int m = i * SUBSTRIDE;
        const float* r0 = mem + (size_t)m * DIM;
        float a0 = 0.f, a1 = 0.f, a2 = 0.f, a3 = 0.f;
        #pragma unroll
        for (int k = 0; k < DIM; k += 4) {
            a0 = fmaf(xr[k],   r0[k],   a0);
            a1 = fmaf(xr[k+1], r0[k+1], a1);
            a2 = fmaf(xr[k+2], r0[k+2], a2);
            a3 = fmaf(xr[k+3], r0[k+3], a3);
        }
        const float s0 = (a0 + a1) + (a2 + a3);
        TOPK_UPDATE(s0, m)
    }
    const size_t base = ((size_t)row * SUB_NBLK + blockIdx.x) * KNN;
    #pragma unroll
    for (int k = 0; k < KNN; ++k) { scv[base + k] = tv[k]; sci[base + k] = tix[k]; }
}

// ---------------------------------------------------------------------------
// per-row: 8th-largest of subsample candidates -> threshold (margin folded in)
// ---------------------------------------------------------------------------
__global__ __launch_bounds__(256) void sub_merge(
    const float* __restrict__ scv, const int* __restrict__ sci,
    float* __restrict__ t)
{
    const int row = blockIdx.x;
    const int tid = threadIdx.x;
    const int NC = SUB_NBLK * KNN;   // 4096
    __shared__ float sv[SUB_NBLK * KNN];
    __shared__ int   si[SUB_NBLK * KNN];
    __shared__ float rv[256];
    __shared__ int   ri[256];
    __shared__ float bestv[KNN];

    for (int i = tid; i < NC; i += 256) {
        sv[i] = scv[(size_t)row * NC + i];
        si[i] = sci[(size_t)row * NC + i];
    }
    __syncthreads();
    for (int it = 0; it < KNN; ++it) {
        float lv = -1e30f; int li = 0x7fffffff;
        for (int i = tid; i < NC; i += 256) {
            const float v = sv[i]; const int ix = si[i];
            if (v > lv || (v == lv && ix < li)) { lv = v; li = ix; }
        }
        rv[tid] = lv; ri[tid] = li;
        __syncthreads();
        for (int s = 128; s > 0; s >>= 1) {
            if (tid < s) {
                const float v = rv[tid + s]; const int ix = ri[tid + s];
                if (v > rv[tid] || (v == rv[tid] && ix < ri[tid])) { rv[tid] = v; ri[tid] = ix; }
            }
            __syncthreads();
        }
        if (tid == 0) bestv[it] = rv[0];
        __syncthreads();
        const int sel = ri[0];
        for (int i = tid; i < NC; i += 256)
            if (si[i] == sel) sv[i] = -1e30f;
        __syncthreads();
    }
    if (tid == 0) t[row] = bestv[KNN - 1] - MARGIN;
}

// ---------------------------------------------------------------------------
// bf16 MFMA GEMM over all 500000 rows with threshold filter -> candidate lists
// block = 4 waves stacked on M (each wave: 64 x-rows); per iter: 16 mem rows
// ---------------------------------------------------------------------------
__global__ __launch_bounds__(256) void gemm_filter(
    const unsigned short* __restrict__ xb, const unsigned short* __restrict__ mb,
    const float* __restrict__ t, int* __restrict__ cnt, int* __restrict__ cand)
{
    const int lane  = threadIdx.x & 63;
    const int wv    = threadIdx.x >> 6;
    const int l15   = lane & 15;
    const int lk    = lane >> 4;
    const int mbase = wv * 64;

    bf16x8 a[4][4];
    #pragma unroll
    for (int mt = 0; mt < 4; ++mt)
        #pragma unroll
        for (int ks = 0; ks < 4; ++ks)
            a[mt][ks] = *reinterpret_cast<const bf16x8*>(
                xb + (size_t)(mbase + mt * 16 + l15) * DIM + ks * 32 + lk * 8);

    float tm[4][4];
    #pragma unroll
    for (int mt = 0; mt < 4; ++mt)
        #pragma unroll
        for (int r = 0; r < 4; ++r)
            tm[mt][r] = t[mbase + mt * 16 + lk * 4 + r];

    for (int c = blockIdx.x; c < NCHUNK; c += gridDim.x) {
        const int n0 = c * 16;
        const size_t brow = (size_t)(n0 + l15) * DIM + lk * 8;
        f32x4 acc[4];
        #pragma unroll
        for (int mt = 0; mt < 4; ++mt) acc[mt] = (f32x4){0.f, 0.f, 0.f, 0.f};
        #pragma unroll
        for (int ks = 0; ks < 4; ++ks) {
            const bf16x8 b = *reinterpret_cast<const bf16x8*>(mb + brow + ks * 32);
            #pragma unroll
            for (int mt = 0; mt < 4; ++mt)
                acc[mt] = __builtin_amdgcn_mfma_f32_16x16x32_bf16(a[mt][ks], b, acc[mt], 0, 0, 0);
        }
        bool anyhit = false;
        #pragma unroll
        for (int mt = 0; mt < 4; ++mt)
            #pragma unroll
            for (int r = 0; r < 4; ++r)
                anyhit |= (acc[mt][r] >= tm[mt][r]);
        if (__any(anyhit)) {
            #pragma unroll
            for (int mt = 0; mt < 4; ++mt)
                #pragma unroll
                for (int r = 0; r < 4; ++r)
                    if (acc[mt][r] >= tm[mt][r]) {
                        const int m = mbase + mt * 16 + lk * 4 + r;
                        const int p = atomicAdd(&cnt[m], 1);
                        if (p < CAP) cand[(size_t)m * CAP + p] = n0 + l15;
                    }
        }
    }
}

// ---------------------------------------------------------------------------
// exact f32 rescore of candidates, extract exact top-8, pos_logit + dm_bs
// ---------------------------------------------------------------------------
__global__ __launch_bounds__(256) void rescore(
    const float* __restrict__ x, const float* __restrict__ mem,
    const int* __restrict__ cnt, const int* __restrict__ cand,
    float* __restrict__ pos_logit, float* __restrict__ dm_bs)
{
    const int row = blockIdx.x;
    const int tid = threadIdx.x;
    __shared__ float sv[CAP];
    __shared__ int   si[CAP];
    __shared__ float xr[DIM];
    __shared__ float rv[256];
    __shared__ int   ri[256];
    __shared__ float bestv[KNN];
    __shared__ int   besti[KNN];

    if (tid < DIM) xr[tid] = x[row * DIM + tid];
    __syncthreads();
    const int c = min(cnt[row], CAP);
    for (int i = tid; i < CAP; i += 256) {
        float v = -1e30f; int m = 0x7fffffff;
        if (i < c) {
            m = cand[(size_t)row * CAP + i];
            const float* mr = mem + (size_t)m * DIM;
            float a0 = 0.f, a1 = 0.f, a2 = 0.f, a3 = 0.f;
            #pragma unroll
            for (int k = 0; k < DIM; k += 4) {
                const float4 mv = *reinterpret_cast<const float4*>(mr + k);
                a0 = fmaf(xr[k],   mv.x, a0);
                a1 = fmaf(xr[k+1], mv.y, a1);
                a2 = fmaf(xr[k+2], mv.z, a2);
                a3 = fmaf(xr[k+3], mv.w, a3);
            }
            v = (a0 + a1) + (a2 + a3);
        }
        sv[i] = v; si[i] = m;
    }
    __syncthreads();

    for (int it = 0; it < KNN; ++it) {
        float lv = -1e30f; int li = 0x7fffffff;
        for (int i = tid; i < CAP; i += 256) {
            const float v = sv[i]; const int ix = si[i];
            if (v > lv || (v == lv && ix < li)) { lv = v; li = ix; }
        }
        rv[tid] = lv; ri[tid] = li;
        __syncthreads();
        for (int s = 128; s > 0; s >>= 1) {
            if (tid < s) {
                const float v = rv[tid + s]; const int ix = ri[tid + s];
                if (v > rv[tid] || (v == rv[tid] && ix < ri[tid])) { rv[tid] = v; ri[tid] = ix; }
            }
            __syncthreads();
        }
        if (tid == 0) { bestv[it] = rv[0]; besti[it] = ri[0]; }
        __syncthreads();
        const int sel = ri[0];
        for (int i = tid; i < CAP; i += 256)
            if (si[i] == sel) sv[i] = -1e30f;
        __syncthreads();
    }

    if (tid == 0) {
        float s = 0.f;
        #pragma unroll
        for (int k = 0; k < KNN; ++k) s += bestv[k];
        pos_logit[row] = s / (float)KNN;
    }
    if (tid < DIM) {
        float s = 0.f;
        #pragma unroll
        for (int k = 0; k < KNN; ++k) s += mem[(size_t)besti[k] * DIM + tid];
        dm_bs[(size_t)row * DIM + tid] = s / (float)KNN;
    }
}

// ---------------------------------------------------------------------------
// neg logits + exp(logits/T) raw into d_out, per-row sum
// ---------------------------------------------------------------------------
__global__ __launch_bounds__(256) void neg_exp(
    const float* __restrict__ x, const int* __restrict__ neg_indices,
    const float* __restrict__ pos_logit,
    float* __restrict__ outs_raw, float* __restrict__ rowsum)
{
    const int b = blockIdx.x, tid = threadIdx.x;
    __shared__ float xb[DIM];
    if (tid < DIM) xb[tid] = x[b * DIM + tid];
    __syncthreads();

    float raw = 0.f;
    if (tid < NLOG) {
        float lg;
        if (tid == 0) {
            lg = pos_logit[b];
        } else {
            const int n = neg_indices[b * NNEG + (tid - 1)];
            const float* xn = x + (size_t)n * DIM;
            float a0 = 0.f, a1 = 0.f, a2 = 0.f, a3 = 0.f;
            #pragma unroll
            for (int k = 0; k < DIM; k += 4) {
                a0 = fmaf(xb[k],   xn[k],   a0);
                a1 = fmaf(xb[k+1], xn[k+1], a1);
                a2 = fmaf(xb[k+2], xn[k+2], a2);
                a3 = fmaf(xb[k+3], xn[k+3], a3);
            }
            lg = (a0 + a1) + (a2 + a3);
        }
        raw = expf(lg / 0.07f);
        outs_raw[(size_t)b * NLOG + tid] = raw;
    }

    __shared__ float red[256];
    red[tid] = raw;
    __syncthreads();
    for (int s = 128; s > 0; s >>= 1) {
        if (tid < s) red[tid] += red[tid + s];
        __syncthreads();
    }
    if (tid == 0) rowsum[b] = red[0];
}

// ---------------------------------------------------------------------------
// Z from rowsums, probs (Z cancels), scale outs in-place
// ---------------------------------------------------------------------------
__global__ __launch_bounds__(256) void finalize(
    float* __restrict__ outs, const float* __restrict__ rowsum)
{
    const int tid = threadIdx.x;  // 256 = BSZ
    __shared__ float red[256];
    __shared__ float Zs;
    const float rs = rowsum[tid];
    red[tid] = rs;
    __syncthreads();
    for (int s = 128; s > 0; s >>= 1) {
        if (tid < s) red[tid] += red[tid + s];
        __syncthreads();
    }
    if (tid == 0) Zs = red[0] / (float)(BSZ * NLOG) * (float)NLENC;
    __syncthreads();
    const float Z = Zs;

    const float ratio = outs[(size_t)tid * NLOG] / rs;
    __syncthreads();
    red[tid] = ratio;
    __syncthreads();
    for (int s = 128; s > 0; s >>= 1) {
        if (tid < s) red[tid] += red[tid + s];
        __syncthreads();
    }
    if (tid == 0) outs[BSZ * NLOG] = red[0] / (float)BSZ;

    for (int i = tid; i < BSZ * NLOG; i += 256) outs[i] /= Z;
}

// ---------------------------------------------------------------------------
// EMA-updated rows -> small ws (before the big copy overwrites scratch)
// ---------------------------------------------------------------------------
__global__ __launch_bounds__(128) void update_rows(
    const float* __restrict__ mem, const int* __restrict__ idxs,
    const float* __restrict__ dm_bs, float* __restrict__ upd)
{
    const int j = blockIdx.x;    // 0..63
    const int d = threadIdx.x;   // 0..127
    float nd = 0.f;
    #pragma unroll
    for (int c = 0; c < CLIPS; ++c) nd += dm_bs[(size_t)(c * BATCH + j) * DIM + d];
    nd *= (1.0f / CLIPS);
    const float old = mem[(size_t)idxs[j] * DIM + d];
    const float v = old * 0.5f + 0.5f * nd;
    __shared__ float red[128];
    red[d] = v * v;
    __syncthreads();
    for (int s = 64; s > 0; s >>= 1) {
        if (d < s) red[d] += red[d + s];
        __syncthreads();
    }
    upd[(size_t)j * DIM + d] = v / sqrtf(red[0]);
}

// ---------------------------------------------------------------------------
// bulk copy memory -> out
// ---------------------------------------------------------------------------
__global__ __launch_bounds__(256) void copy_mem(
    const float* __restrict__ src, float* __restrict__ dst, int n)
{
    int i = blockIdx.x * blockDim.x + threadIdx.x;
    const int stride = gridDim.x * blockDim.x;
    for (; i < n; i += stride) dst[i] = src[i];
}

// ---------------------------------------------------------------------------
// scatter updated rows (last-duplicate wins, matching .at[].set)
// ---------------------------------------------------------------------------
__global__ __launch_bounds__(128) void scatter_rows(
    const int* __restrict__ idxs, const float* __restrict__ upd,
    float* __restrict__ out_mem)
{
    const int j = blockIdx.x;
    const int d = threadIdx.x;
    const int my = idxs[j];
    for (int jj = j + 1; jj < BATCH; ++jj)
        if (idxs[jj] == my) return;
    out_mem[(size_t)my * DIM + d] = upd[(size_t)j * DIM + d];
}

extern "C" void kernel_launch(void* const* d_in, const int* in_sizes, int n_in,
                              void* d_out, int out_size, void* d_ws, size_t ws_size,
                              hipStream_t stream)
{
    const float* x    = (const float*)d_in[0];
    const int*   idxs = (const int*)d_in[1];
    const int*   neg  = (const int*)d_in[2];
    const float* mem  = (const float*)d_in[3];

    float* out     = (float*)d_out;
    float* out_mem = out + (size_t)BSZ * NLOG + 1;      // 64,000,000 floats

    // scratch inside the not-yet-written out_mem region (16B-aligned base)
    float* S = out + 65536;
    unsigned short* mem_bf = (unsigned short*)S;                 // 64M ushort = 32M floats
    unsigned short* x_bf   = (unsigned short*)(S + 32000000);    // 32768 ushort
    float* scv   = S + 32000000 + 16384;                         // 256*4096
    int*   sci   = (int*)(scv + (size_t)BSZ * SUB_NBLK * KNN);   // 256*4096
    float* t     = scv + 2 * (size_t)BSZ * SUB_NBLK * KNN;       // 256
    int*   cnt   = (int*)(t + BSZ);                              // 256
    int*   cand  = cnt + BSZ;                                    // 256*4096
    float* pos   = (float*)(cand + (size_t)BSZ * CAP);           // 256
    float* dm_bs = pos + BSZ;                                    // 32768
    float* rowsum= dm_bs + (size_t)BSZ * DIM;                    // 256
    float* upd   = (float*)d_ws;                                 // 8192 floats

    hipLaunchKernelGGL(convert_bf16, dim3(2048), dim3(256), 0, stream, mem, mem_bf, NLENC * DIM);
    hipLaunchKernelGGL(convert_bf16, dim3(32),   dim3(256), 0, stream, x, x_bf, BSZ * DIM);
    hipLaunchKernelGGL(sub_topk,     dim3(SUB_NBLK), dim3(256), 0, stream, x, mem, scv, sci);
    hipLaunchKernelGGL(sub_merge,    dim3(BSZ),  dim3(256), 0, stream, scv, sci, t);
    hipMemsetAsync(cnt, 0, BSZ * sizeof(int), stream);
    hipLaunchKernelGGL(gemm_filter,  dim3(2048), dim3(256), 0, stream, x_bf, mem_bf, t, cnt, cand);
    hipLaunchKernelGGL(rescore,      dim3(BSZ),  dim3(256), 0, stream, x, mem, cnt, cand, pos, dm_bs);
    hipLaunchKernelGGL(neg_exp,      dim3(BSZ),  dim3(256), 0, stream, x, neg, pos, out, rowsum);
    hipLaunchKernelGGL(finalize,     dim3(1),    dim3(256), 0, stream, out, rowsum);
    hipLaunchKernelGGL(update_rows,  dim3(BATCH), dim3(128), 0, stream, mem, idxs, dm_bs, upd);
    hipLaunchKernelGGL(copy_mem,     dim3(2048), dim3(256), 0, stream, mem, out_mem, NLENC * DIM);
    hipLaunchKernelGGL(scatter_rows, dim3(BATCH), dim3(128), 0, stream, idxs, upd, out_mem);
}

// Round 3
// 425.230 us; speedup vs baseline: 5.6576x; 1.3622x over previous
//
#include <hip/hip_runtime.h>

#define NLENC 500000
#define DIM   128
#define BSZ   256     // BATCH_SIZE * CLIPS_NUM
#define BATCH 64
#define CLIPS 4
#define NNEG  252     // (BATCH-1)*CLIPS
#define NLOG  253
#define KNN   8

#define SUBSTRIDE 64
#define SUBN      7813          // ceil(500000/64)
#define SUB_NBLK  512
#define SUB_ROWS  16
#define CAP       4096
#define MARGIN    0.006f

#define NB          64                        // memory rows per tile
#define NTILE       ((NLENC + NB - 1) / NB)   // 7813 (last tile: 32 rows)
#define GEMM_BLOCKS 768                       // 3 blocks/CU

typedef short bf16x8 __attribute__((ext_vector_type(8)));
typedef float f32x4  __attribute__((ext_vector_type(4)));

__device__ inline unsigned short f2bf(float f) {
    unsigned int u = __float_as_uint(f);
    u += 0x7fffu + ((u >> 16) & 1u);       // round-to-nearest-even
    return (unsigned short)(u >> 16);
}

// ---------------------------------------------------------------------------
// subsample top-8 (stride-64 rows) in exact f32 — per-row threshold source
// ---------------------------------------------------------------------------
#define TOPK_UPDATE(S, M)                                                  \
    if ((S) > vmin) {                                                      \
        int slot = 0; float mv = tv[0];                                    \
        _Pragma("unroll")                                                  \
        for (int k = 1; k < KNN; ++k) if (tv[k] < mv) { mv = tv[k]; slot = k; } \
        tv[slot] = (S); tix[slot] = (M);                                   \
        vmin = tv[0];                                                      \
        _Pragma("unroll")                                                  \
        for (int k = 1; k < KNN; ++k) vmin = fminf(vmin, tv[k]);           \
    }

__global__ __launch_bounds__(256) void sub_topk(
    const float* __restrict__ x, const float* __restrict__ mem,
    float* __restrict__ scv, int* __restrict__ sci)
{
    const int row = threadIdx.x;
    float xr[DIM];
    #pragma unroll
    for (int k = 0; k < DIM; k += 4) {
        const float4 v = *reinterpret_cast<const float4*>(x + row * DIM + k);
        xr[k] = v.x; xr[k+1] = v.y; xr[k+2] = v.z; xr[k+3] = v.w;
    }
    float tv[KNN]; int tix[KNN];
    #pragma unroll
    for (int k = 0; k < KNN; ++k) { tv[k] = -1e30f; tix[k] = 0; }
    float vmin = -1e30f;

    const int i0 = blockIdx.x * SUB_ROWS;
    const int i1 = min(i0 + SUB_ROWS, SUBN);
    for (int i = i0; i < i1; ++i) {
        const int m = i * SUBSTRIDE;
        const float* r0 = mem + (size_t)m * DIM;
        float a0 = 0.f, a1 = 0.f, a2 = 0.f, a3 = 0.f;
        #pragma unroll
        for (int k = 0; k < DIM; k += 4) {
            a0 = fmaf(xr[k],   r0[k],   a0);
            a1 = fmaf(xr[k+1], r0[k+1], a1);
            a2 = fmaf(xr[k+2], r0[k+2], a2);
            a3 = fmaf(xr[k+3], r0[k+3], a3);
        }
        const float s0 = (a0 + a1) + (a2 + a3);
        TOPK_UPDATE(s0, m)
    }
    const size_t base = ((size_t)row * SUB_NBLK + blockIdx.x) * KNN;
    #pragma unroll
    for (int k = 0; k < KNN; ++k) { scv[base + k] = tv[k]; sci[base + k] = tix[k]; }
}

// ---------------------------------------------------------------------------
// per-row: 8th-largest of subsample candidates -> threshold (margin folded in)
// ---------------------------------------------------------------------------
__global__ __launch_bounds__(256) void sub_merge(
    const float* __restrict__ scv, const int* __restrict__ sci,
    float* __restrict__ t)
{
    const int row = blockIdx.x;
    const int tid = threadIdx.x;
    const int NC = SUB_NBLK * KNN;   // 4096
    __shared__ float sv[SUB_NBLK * KNN];
    __shared__ int   si[SUB_NBLK * KNN];
    __shared__ float rv[256];
    __shared__ int   ri[256];
    __shared__ float bestv[KNN];

    for (int i = tid; i < NC; i += 256) {
        sv[i] = scv[(size_t)row * NC + i];
        si[i] = sci[(size_t)row * NC + i];
    }
    __syncthreads();
    for (int it = 0; it < KNN; ++it) {
        float lv = -1e30f; int li = 0x7fffffff;
        for (int i = tid; i < NC; i += 256) {
            const float v = sv[i]; const int ix = si[i];
            if (v > lv || (v == lv && ix < li)) { lv = v; li = ix; }
        }
        rv[tid] = lv; ri[tid] = li;
        __syncthreads();
        for (int s = 128; s > 0; s >>= 1) {
            if (tid < s) {
                const float v = rv[tid + s]; const int ix = ri[tid + s];
                if (v > rv[tid] || (v == rv[tid] && ix < ri[tid])) { rv[tid] = v; ri[tid] = ix; }
            }
            __syncthreads();
        }
        if (tid == 0) bestv[it] = rv[0];
        __syncthreads();
        const int sel = ri[0];
        for (int i = tid; i < NC; i += 256)
            if (si[i] == sel) sv[i] = -1e30f;
        __syncthreads();
    }
    if (tid == 0) t[row] = bestv[KNN - 1] - MARGIN;
}

// ---------------------------------------------------------------------------
// FUSED: stream memory bank f32 once; per 64-row tile:
//   regs -> dword copy to out_mem (optional) -> cvt bf16 -> swizzled LDS
//   -> MFMA filter vs per-row thresholds -> candidate append
// reg-staged double buffer, one barrier per tile.
// ---------------------------------------------------------------------------
__global__ __launch_bounds__(256, 3) void gemm_filter_f32(
    const float* __restrict__ x, const float* __restrict__ memf,
    const float* __restrict__ t, int* __restrict__ cnt, int* __restrict__ cand,
    float* __restrict__ copy_dst)
{
    __shared__ unsigned short bt[2][NB * DIM];   // 2 x 16 KB bf16 tile
    const int tid  = threadIdx.x;
    const int lane = tid & 63, wv = tid >> 6;
    const int l15  = lane & 15, lk = lane >> 4;
    const int mbase = wv * 64;

    // A fragments: x rows converted to bf16 in-register (held whole kernel)
    bf16x8 a[4][4];
    #pragma unroll
    for (int mt = 0; mt < 4; ++mt)
        #pragma unroll
        for (int ks = 0; ks < 4; ++ks) {
            const float* p = x + (size_t)(mbase + mt * 16 + l15) * DIM + ks * 32 + lk * 8;
            const float4 lo = *reinterpret_cast<const float4*>(p);
            const float4 hi = *reinterpret_cast<const float4*>(p + 4);
            bf16x8 v;
            v[0] = f2bf(lo.x); v[1] = f2bf(lo.y); v[2] = f2bf(lo.z); v[3] = f2bf(lo.w);
            v[4] = f2bf(hi.x); v[5] = f2bf(hi.y); v[6] = f2bf(hi.z); v[7] = f2bf(hi.w);
            a[mt][ks] = v;
        }
    float tm[4][4];
    #pragma unroll
    for (int mt = 0; mt < 4; ++mt)
        #pragma unroll
        for (int r = 0; r < 4; ++r)
            tm[mt][r] = t[mbase + mt * 16 + lk * 4 + r];

    float4 slo[4], shi[4];   // staging regs: 32 floats = one tile / 256 threads

    auto LOADT = [&](int tt) {
        const size_t gb = (size_t)tt * (NB * DIM);
        #pragma unroll
        for (int i = 0; i < 4; ++i) {
            size_t e = gb + (size_t)((i * 512 + 2 * tid) * 4);
            if (e > (size_t)(NLENC * DIM - 8)) e = (size_t)(NLENC * DIM - 8);  // tail clamp
            slo[i] = *reinterpret_cast<const float4*>(memf + e);
            shi[i] = *reinterpret_cast<const float4*>(memf + e + 4);
        }
    };
    auto STORE_LDS = [&](int buf) {
        char* base = reinterpret_cast<char*>(&bt[buf][0]);
        #pragma unroll
        for (int i = 0; i < 4; ++i) {
            const int e0   = (i * 512 + 2 * tid) * 4;       // bf16 elem idx in tile
            const int row  = e0 >> 7;
            const int byte = (e0 * 2) ^ ((row & 7) << 4);   // T2 XOR swizzle
            bf16x8 v;
            v[0] = f2bf(slo[i].x); v[1] = f2bf(slo[i].y); v[2] = f2bf(slo[i].z); v[3] = f2bf(slo[i].w);
            v[4] = f2bf(shi[i].x); v[5] = f2bf(shi[i].y); v[6] = f2bf(shi[i].z); v[7] = f2bf(shi[i].w);
            *reinterpret_cast<bf16x8*>(base + byte) = v;
        }
    };
    auto COPYT = [&](int tt) {
        if (!copy_dst) return;
        const size_t gb = (size_t)tt * (NB * DIM);
        #pragma unroll
        for (int i = 0; i < 4; ++i) {
            const size_t g = gb + (size_t)((i * 512 + 2 * tid) * 4);
            if (g < (size_t)NLENC * DIM) {   // chunks never straddle the end (both mult of 8)
                float* d = copy_dst + g;     // 4B-aligned dst -> dword stores
                d[0] = slo[i].x; d[1] = slo[i].y; d[2] = slo[i].z; d[3] = slo[i].w;
                d[4] = shi[i].x; d[5] = shi[i].y; d[6] = shi[i].z; d[7] = shi[i].w;
            }
        }
    };
    auto COMPUTE = [&](int buf, int tt) {
        const char* base = reinterpret_cast<const char*>(&bt[buf][0]);
        const int n0 = tt * NB;
        #pragma unroll
        for (int nt = 0; nt < 4; ++nt) {
            const int row = nt * 16 + l15;
            bf16x8 b[4];
            #pragma unroll
            for (int ks = 0; ks < 4; ++ks) {
                const int byte = (row * 256 + ks * 64 + lk * 16) ^ ((row & 7) << 4);
                b[ks] = *reinterpret_cast<const bf16x8*>(base + byte);
            }
            f32x4 acc[4];
            #pragma unroll
            for (int mt = 0; mt < 4; ++mt) acc[mt] = (f32x4){0.f, 0.f, 0.f, 0.f};
            #pragma unroll
            for (int ks = 0; ks < 4; ++ks)
                #pragma unroll
                for (int mt = 0; mt < 4; ++mt)
                    acc[mt] = __builtin_amdgcn_mfma_f32_16x16x32_bf16(a[mt][ks], b[ks], acc[mt], 0, 0, 0);
            unsigned hm = 0;
            #pragma unroll
            for (int mt = 0; mt < 4; ++mt)
                #pragma unroll
                for (int r = 0; r < 4; ++r)
                    if (acc[mt][r] >= tm[mt][r]) hm |= 1u << (mt * 4 + r);
            const int n = n0 + nt * 16 + l15;
            if (n < NLENC) {
                while (hm) {
                    const int bp = __ffs(hm) - 1; hm &= hm - 1;
                    const int m = mbase + (bp >> 2) * 16 + lk * 4 + (bp & 3);
                    const int p = atomicAdd(&cnt[m], 1);
                    if (p < CAP) cand[(size_t)m * CAP + p] = n;
                }
            }
        }
    };

    int tile = blockIdx.x;
    LOADT(tile);
    STORE_LDS(0);
    COPYT(tile);
    __syncthreads();
    int cur = 0;
    while (tile < NTILE) {
        const int nxt = tile + GEMM_BLOCKS;
        const bool more = (nxt < NTILE);
        if (more) LOADT(nxt);            // async loads hide under COMPUTE
        COMPUTE(cur, tile);
        if (more) { STORE_LDS(cur ^ 1); COPYT(nxt); }
        __syncthreads();                 // single barrier per tile
        cur ^= 1;
        tile = nxt;
    }
}

// ---------------------------------------------------------------------------
// exact f32 rescore of candidates, extract exact top-8, pos_logit + dm_bs
// ---------------------------------------------------------------------------
__global__ __launch_bounds__(256) void rescore(
    const float* __restrict__ x, const float* __restrict__ mem,
    const int* __restrict__ cnt, const int* __restrict__ cand,
    float* __restrict__ pos_logit, float* __restrict__ dm_bs)
{
    const int row = blockIdx.x;
    const int tid = threadIdx.x;
    __shared__ float sv[CAP];
    __shared__ int   si[CAP];
    __shared__ float xr[DIM];
    __shared__ float rv[256];
    __shared__ int   ri[256];
    __shared__ float bestv[KNN];
    __shared__ int   besti[KNN];

    if (tid < DIM) xr[tid] = x[row * DIM + tid];
    __syncthreads();
    const int c = min(cnt[row], CAP);
    for (int i = tid; i < CAP; i += 256) {
        float v = -1e30f; int m = 0x7fffffff;
        if (i < c) {
            m = cand[(size_t)row * CAP + i];
            const float* mr = mem + (size_t)m * DIM;
            float a0 = 0.f, a1 = 0.f, a2 = 0.f, a3 = 0.f;
            #pragma unroll
            for (int k = 0; k < DIM; k += 4) {
                const float4 mv = *reinterpret_cast<const float4*>(mr + k);
                a0 = fmaf(xr[k],   mv.x, a0);
                a1 = fmaf(xr[k+1], mv.y, a1);
                a2 = fmaf(xr[k+2], mv.z, a2);
                a3 = fmaf(xr[k+3], mv.w, a3);
            }
            v = (a0 + a1) + (a2 + a3);
        }
        sv[i] = v; si[i] = m;
    }
    __syncthreads();

    for (int it = 0; it < KNN; ++it) {
        float lv = -1e30f; int li = 0x7fffffff;
        for (int i = tid; i < CAP; i += 256) {
            const float v = sv[i]; const int ix = si[i];
            if (v > lv || (v == lv && ix < li)) { lv = v; li = ix; }
        }
        rv[tid] = lv; ri[tid] = li;
        __syncthreads();
        for (int s = 128; s > 0; s >>= 1) {
            if (tid < s) {
                const float v = rv[tid + s]; const int ix = ri[tid + s];
                if (v > rv[tid] || (v == rv[tid] && ix < ri[tid])) { rv[tid] = v; ri[tid] = ix; }
            }
            __syncthreads();
        }
        if (tid == 0) { bestv[it] = rv[0]; besti[it] = ri[0]; }
        __syncthreads();
        const int sel = ri[0];
        for (int i = tid; i < CAP; i += 256)
            if (si[i] == sel) sv[i] = -1e30f;
        __syncthreads();
    }

    if (tid == 0) {
        float s = 0.f;
        #pragma unroll
        for (int k = 0; k < KNN; ++k) s += bestv[k];
        pos_logit[row] = s / (float)KNN;
    }
    if (tid < DIM) {
        float s = 0.f;
        #pragma unroll
        for (int k = 0; k < KNN; ++k) s += mem[(size_t)besti[k] * DIM + tid];
        dm_bs[(size_t)row * DIM + tid] = s / (float)KNN;
    }
}

// ---------------------------------------------------------------------------
// neg logits + exp(logits/T) raw into d_out, per-row sum
// ---------------------------------------------------------------------------
__global__ __launch_bounds__(256) void neg_exp(
    const float* __restrict__ x, const int* __restrict__ neg_indices,
    const float* __restrict__ pos_logit,
    float* __restrict__ outs_raw, float* __restrict__ rowsum)
{
    const int b = blockIdx.x, tid = threadIdx.x;
    __shared__ float xb[DIM];
    if (tid < DIM) xb[tid] = x[b * DIM + tid];
    __syncthreads();

    float raw = 0.f;
    if (tid < NLOG) {
        float lg;
        if (tid == 0) {
            lg = pos_logit[b];
        } else {
            const int n = neg_indices[b * NNEG + (tid - 1)];
            const float* xn = x + (size_t)n * DIM;
            float a0 = 0.f, a1 = 0.f, a2 = 0.f, a3 = 0.f;
            #pragma unroll
            for (int k = 0; k < DIM; k += 4) {
                a0 = fmaf(xb[k],   xn[k],   a0);
                a1 = fmaf(xb[k+1], xn[k+1], a1);
                a2 = fmaf(xb[k+2], xn[k+2], a2);
                a3 = fmaf(xb[k+3], xn[k+3], a3);
            }
            lg = (a0 + a1) + (a2 + a3);
        }
        raw = expf(lg / 0.07f);
        outs_raw[(size_t)b * NLOG + tid] = raw;
    }

    __shared__ float red[256];
    red[tid] = raw;
    __syncthreads();
    for (int s = 128; s > 0; s >>= 1) {
        if (tid < s) red[tid] += red[tid + s];
        __syncthreads();
    }
    if (tid == 0) rowsum[b] = red[0];
}

// ---------------------------------------------------------------------------
// Z from rowsums, probs (Z cancels), scale outs in-place
// ---------------------------------------------------------------------------
__global__ __launch_bounds__(256) void finalize(
    float* __restrict__ outs, const float* __restrict__ rowsum)
{
    const int tid = threadIdx.x;  // 256 = BSZ
    __shared__ float red[256];
    __shared__ float Zs;
    const float rs = rowsum[tid];
    red[tid] = rs;
    __syncthreads();
    for (int s = 128; s > 0; s >>= 1) {
        if (tid < s) red[tid] += red[tid + s];
        __syncthreads();
    }
    if (tid == 0) Zs = red[0] / (float)(BSZ * NLOG) * (float)NLENC;
    __syncthreads();
    const float Z = Zs;

    const float ratio = outs[(size_t)tid * NLOG] / rs;
    __syncthreads();
    red[tid] = ratio;
    __syncthreads();
    for (int s = 128; s > 0; s >>= 1) {
        if (tid < s) red[tid] += red[tid + s];
        __syncthreads();
    }
    if (tid == 0) outs[BSZ * NLOG] = red[0] / (float)BSZ;

    for (int i = tid; i < BSZ * NLOG; i += 256) outs[i] /= Z;
}

// ---------------------------------------------------------------------------
// EMA-updated rows -> upd buffer
// ---------------------------------------------------------------------------
__global__ __launch_bounds__(128) void update_rows(
    const float* __restrict__ mem, const int* __restrict__ idxs,
    const float* __restrict__ dm_bs, float* __restrict__ upd)
{
    const int j = blockIdx.x;    // 0..63
    const int d = threadIdx.x;   // 0..127
    float nd = 0.f;
    #pragma unroll
    for (int c = 0; c < CLIPS; ++c) nd += dm_bs[(size_t)(c * BATCH + j) * DIM + d];
    nd *= (1.0f / CLIPS);
    const float old = mem[(size_t)idxs[j] * DIM + d];
    const float v = old * 0.5f + 0.5f * nd;
    __shared__ float red[128];
    red[d] = v * v;
    __syncthreads();
    for (int s = 64; s > 0; s >>= 1) {
        if (d < s) red[d] += red[d + s];
        __syncthreads();
    }
    upd[(size_t)j * DIM + d] = v / sqrtf(red[0]);
}

// ---------------------------------------------------------------------------
// bulk copy memory -> out (fallback path only)
// ---------------------------------------------------------------------------
__global__ __launch_bounds__(256) void copy_mem(
    const float* __restrict__ src, float* __restrict__ dst, int n)
{
    int i = blockIdx.x * blockDim.x + threadIdx.x;
    const int stride = gridDim.x * blockDim.x;
    for (; i < n; i += stride) dst[i] = src[i];
}

// ---------------------------------------------------------------------------
// scatter updated rows (last-duplicate wins, matching .at[].set)
// ---------------------------------------------------------------------------
__global__ __launch_bounds__(128) void scatter_rows(
    const int* __restrict__ idxs, const float* __restrict__ upd,
    float* __restrict__ out_mem)
{
    const int j = blockIdx.x;
    const int d = threadIdx.x;
    const int my = idxs[j];
    for (int jj = j + 1; jj < BATCH; ++jj)
        if (idxs[jj] == my) return;
    out_mem[(size_t)my * DIM + d] = upd[(size_t)j * DIM + d];
}

extern "C" void kernel_launch(void* const* d_in, const int* in_sizes, int n_in,
                              void* d_out, int out_size, void* d_ws, size_t ws_size,
                              hipStream_t stream)
{
    const float* x    = (const float*)d_in[0];
    const int*   idxs = (const int*)d_in[1];
    const int*   neg  = (const int*)d_in[2];
    const float* mem  = (const float*)d_in[3];

    float* out     = (float*)d_out;
    float* out_mem = out + (size_t)BSZ * NLOG + 1;      // 64,000,000 floats

    // sub-topk scratch lives in out region; consumed before gemm writes out_mem
    float* S   = out + 65536;
    float* scv = S;                                              // 256*4096 f
    int*   sci = (int*)(scv + (size_t)BSZ * SUB_NBLK * KNN);     // 256*4096 i

    const size_t NEED = (size_t)BSZ * CAP * 4      // cand
                      + (size_t)BSZ * DIM * 4      // dm_bs
                      + (size_t)BATCH * DIM * 4    // upd
                      + 4 * BSZ * 4;               // t, cnt, pos, rowsum

    if (ws_size >= NEED) {
        // ---- fused path: scratch in d_ws, copy fused into gemm ----
        char*  W      = (char*)d_ws;
        int*   cand   = (int*)W;
        float* dm_bs  = (float*)(W + (size_t)BSZ * CAP * 4);
        float* upd    = dm_bs + (size_t)BSZ * DIM;
        float* t      = upd + (size_t)BATCH * DIM;
        int*   cnt    = (int*)(t + BSZ);
        float* pos    = (float*)(cnt + BSZ);
        float* rowsum = pos + BSZ;

        hipLaunchKernelGGL(sub_topk,  dim3(SUB_NBLK), dim3(256), 0, stream, x, mem, scv, sci);
        hipLaunchKernelGGL(sub_merge, dim3(BSZ),  dim3(256), 0, stream, scv, sci, t);
        hipMemsetAsync(cnt, 0, BSZ * sizeof(int), stream);
        hipLaunchKernelGGL(gemm_filter_f32, dim3(GEMM_BLOCKS), dim3(256), 0, stream,
                           x, mem, t, cnt, cand, out_mem);
        hipLaunchKernelGGL(rescore,   dim3(BSZ),  dim3(256), 0, stream, x, mem, cnt, cand, pos, dm_bs);
        hipLaunchKernelGGL(neg_exp,   dim3(BSZ),  dim3(256), 0, stream, x, neg, pos, out, rowsum);
        hipLaunchKernelGGL(finalize,  dim3(1),    dim3(256), 0, stream, out, rowsum);
        hipLaunchKernelGGL(update_rows, dim3(BATCH), dim3(128), 0, stream, mem, idxs, dm_bs, upd);
        hipLaunchKernelGGL(scatter_rows, dim3(BATCH), dim3(128), 0, stream, idxs, upd, out_mem);
    } else {
        // ---- fallback: scratch in out region (overwritten by copy_mem later) ----
        float* t      = (float*)(sci + (size_t)BSZ * SUB_NBLK * KNN);
        int*   cnt    = (int*)(t + BSZ);
        int*   cand   = cnt + BSZ;
        float* pos    = (float*)(cand + (size_t)BSZ * CAP);
        float* dm_bs  = pos + BSZ;
        float* rowsum = dm_bs + (size_t)BSZ * DIM;
        float* upd    = (float*)d_ws;   // 32 KB

        hipLaunchKernelGGL(sub_topk,  dim3(SUB_NBLK), dim3(256), 0, stream, x, mem, scv, sci);
        hipLaunchKernelGGL(sub_merge, dim3(BSZ),  dim3(256), 0, stream, scv, sci, t);
        hipMemsetAsync(cnt, 0, BSZ * sizeof(int), stream);
        hipLaunchKernelGGL(gemm_filter_f32, dim3(GEMM_BLOCKS), dim3(256), 0, stream,
                           x, mem, t, cnt, cand, (float*)nullptr);
        hipLaunchKernelGGL(rescore,   dim3(BSZ),  dim3(256), 0, stream, x, mem, cnt, cand, pos, dm_bs);
        hipLaunchKernelGGL(neg_exp,   dim3(BSZ),  dim3(256), 0, stream, x, neg, pos, out, rowsum);
        hipLaunchKernelGGL(finalize,  dim3(1),    dim3(256), 0, stream, out, rowsum);
        hipLaunchKernelGGL(update_rows, dim3(BATCH), dim3(128), 0, stream, mem, idxs, dm_bs, upd);
        hipLaunchKernelGGL(copy_mem,  dim3(2048), dim3(256), 0, stream, mem, out_mem, NLENC * DIM);
        hipLaunchKernelGGL(scatter_rows, dim3(BATCH), dim3(128), 0, stream, idxs, upd, out_mem);
    }
}